// Round 1
// baseline (721.787 us; speedup 1.0000x reference)
//
#include <hip/hip_runtime.h>
#include <stdint.h>

// SmallMLP_INR: fused 6-layer MLP (2->256->256x4->1, ReLU) over 524288 points.
// Strategy: split-bf16 MFMA (x = hi + lo, truncate split). Y = Xh*Wh + Xh*Wl + Xl*Wh
// in fp32 accumulators -> ~2^-16 relative error, ~100x under the 1.99e-4 threshold.
// Block = 64 points, activations resident in LDS (hi/lo bf16, XOR-swizzled, 64 KB
// total -> 2 blocks/CU). Weights pre-packed into MFMA B-fragment order in d_ws.

#define WIDTH 256
#define MT 64

typedef short short8 __attribute__((ext_vector_type(8)));
typedef float float4v __attribute__((ext_vector_type(4)));

// truncate-split f32 -> bf16 hi + bf16 lo (lo also truncated; total ~16-17 bits)
__device__ __forceinline__ void split_bf(float f, unsigned short &hi, unsigned short &lo) {
    union { float f; uint32_t u; } a; a.f = f;
    hi = (unsigned short)(a.u >> 16);
    union { uint32_t u; float f; } h; h.u = a.u & 0xffff0000u;
    union { float f; uint32_t u; } d; d.f = f - h.f;   // exact (Sterbenz)
    lo = (unsigned short)(d.u >> 16);
}

__device__ __forceinline__ float bf2f(unsigned short h) {
    union { uint32_t u; float f; } a; a.u = ((uint32_t)h) << 16; return a.f;
}

// LDS activation addressing: X[m][n], row stride 256 ushorts, 16B-chunk index
// XOR-swizzled by (m&7) -> conflict-free MFMA A-frag reads without padding.
__device__ __forceinline__ int xaddr(int m, int n) {
    int c = n >> 3;
    return m * 256 + (((c ^ (m & 7)) << 3) | (n & 7));
}

// Pack W2..W5 (256x256, row-major [k][n]) into MFMA B-fragment order:
// [l][ct(16)][ks(8)][lane(64)][j(8)], n = 16*ct + (lane&15), k = 32*ks + 8*(lane>>4) + j.
// Separate hi and lo arrays so the hot loop does lane-contiguous 16B loads.
__global__ void prep_weights(const float* __restrict__ W2, const float* __restrict__ W3,
                             const float* __restrict__ W4, const float* __restrict__ W5,
                             unsigned short* __restrict__ whi, unsigned short* __restrict__ wlo) {
    int tid = blockIdx.x * 256 + threadIdx.x;   // 4*65536 total
    int l = tid >> 16;
    int e = tid & 65535;
    int j = e & 7;
    int lane = (e >> 3) & 63;
    int ks = (e >> 9) & 7;
    int ct = (e >> 12) & 15;
    int n = ct * 16 + (lane & 15);
    int k = ks * 32 + (lane >> 4) * 8 + j;
    const float* W = (l == 0) ? W2 : (l == 1) ? W3 : (l == 2) ? W4 : W5;
    float w = W[k * 256 + n];
    unsigned short hi, lo;
    split_bf(w, hi, lo);
    whi[tid] = hi;
    wlo[tid] = lo;
}

__global__ __launch_bounds__(256, 2) void mlp_fused(
    const float* __restrict__ coords,
    const float* __restrict__ W1, const float* __restrict__ b1,
    const float* __restrict__ b2, const float* __restrict__ b3,
    const float* __restrict__ b4, const float* __restrict__ b5,
    const float* __restrict__ W6, const float* __restrict__ b6,
    const unsigned short* __restrict__ whi, const unsigned short* __restrict__ wlo,
    float* __restrict__ out)
{
    __shared__ unsigned short Xhi[64 * 256];   // 32 KB
    __shared__ unsigned short Xlo[64 * 256];   // 32 KB  (total exactly 64 KB)

    const int tid = threadIdx.x;
    const int m0 = blockIdx.x * MT;

    // ---- layer 1: 2 -> 256 (VALU). Thread owns output column n = tid. ----
    {
        const float w0 = W1[tid];           // W1[0][tid]
        const float w1 = W1[WIDTH + tid];   // W1[1][tid]
        const float bb = b1[tid];
        for (int m = 0; m < MT; ++m) {
            float c0 = coords[(m0 + m) * 2];       // uniform address -> s_load
            float c1 = coords[(m0 + m) * 2 + 1];
            float v = fmaf(c0, w0, fmaf(c1, w1, bb));
            v = fmaxf(v, 0.0f);
            unsigned short h, l;
            split_bf(v, h, l);
            int a = xaddr(m, tid);
            Xhi[a] = h;
            Xlo[a] = l;
        }
    }
    __syncthreads();

    const int wv   = tid >> 6;     // wave 0..3 owns output cols [64*wv, 64*wv+64)
    const int lane = tid & 63;
    const int quad = lane >> 4;
    const int l16  = lane & 15;

    // ---- layers 2..5: 256 -> 256 via 16x16x32 bf16 MFMA, 3-product split ----
    for (int l = 0; l < 4; ++l) {
        const float* bias = (l == 0) ? b2 : (l == 1) ? b3 : (l == 2) ? b4 : b5;

        float4v acc[4][4];
        #pragma unroll
        for (int mt = 0; mt < 4; ++mt)
            #pragma unroll
            for (int nt = 0; nt < 4; ++nt)
                acc[mt][nt] = (float4v){0.f, 0.f, 0.f, 0.f};

        #pragma unroll 2
        for (int ks = 0; ks < 8; ++ks) {
            short8 ah[4], al[4], wh[4], wl[4];
            #pragma unroll
            for (int mt = 0; mt < 4; ++mt) {
                // A-frag: A[m][k], m = 16*mt + (lane&15), k = 32*ks + 8*quad + j
                int off = xaddr(16 * mt + l16, 32 * ks + 8 * quad);
                ah[mt] = *(const short8*)(Xhi + off);
                al[mt] = *(const short8*)(Xlo + off);
            }
            #pragma unroll
            for (int nt = 0; nt < 4; ++nt) {
                // B-frag: packed order -> lane-contiguous 16B load
                int idx = ((((l * 16) + (4 * wv + nt)) * 8 + ks) * 64 + lane) * 8;
                wh[nt] = *(const short8*)(whi + idx);
                wl[nt] = *(const short8*)(wlo + idx);
            }
            #pragma unroll
            for (int mt = 0; mt < 4; ++mt)
                #pragma unroll
                for (int nt = 0; nt < 4; ++nt) {
                    acc[mt][nt] = __builtin_amdgcn_mfma_f32_16x16x32_bf16(ah[mt], wh[nt], acc[mt][nt], 0, 0, 0);
                    acc[mt][nt] = __builtin_amdgcn_mfma_f32_16x16x32_bf16(ah[mt], wl[nt], acc[mt][nt], 0, 0, 0);
                    acc[mt][nt] = __builtin_amdgcn_mfma_f32_16x16x32_bf16(al[mt], wh[nt], acc[mt][nt], 0, 0, 0);
                }
        }
        __syncthreads();   // all waves done reading X before overwrite

        // epilogue: bias + ReLU + re-split into LDS
        // D layout: col = lane&15, row = quad*4 + r (within 16x16 tile)
        #pragma unroll
        for (int nt = 0; nt < 4; ++nt) {
            const int n = 64 * wv + 16 * nt + l16;
            const float bb = bias[n];
            #pragma unroll
            for (int mt = 0; mt < 4; ++mt)
                #pragma unroll
                for (int r = 0; r < 4; ++r) {
                    const int m = 16 * mt + 4 * quad + r;
                    float v = acc[mt][nt][r] + bb;
                    v = fmaxf(v, 0.0f);
                    unsigned short h, lo2;
                    split_bf(v, h, lo2);
                    int a = xaddr(m, n);
                    Xhi[a] = h;
                    Xlo[a] = lo2;
                }
        }
        __syncthreads();
    }

    // ---- layer 6: 256 -> 1 (VALU). 4 threads per point, shuffle-reduce. ----
    {
        const int m = tid >> 2;
        const int cq = tid & 3;
        float s = 0.0f;
        #pragma unroll
        for (int g = 0; g < 8; ++g) {
            int nb = cq * 64 + g * 8;
            int a = xaddr(m, nb);
            const short8 hv = *(const short8*)(Xhi + a);
            const short8 lv = *(const short8*)(Xlo + a);
            const float* wp = W6 + nb;
            #pragma unroll
            for (int j = 0; j < 8; ++j) {
                float x = bf2f((unsigned short)hv[j]) + bf2f((unsigned short)lv[j]);
                s = fmaf(x, wp[j], s);
            }
        }
        s += __shfl_xor(s, 1);
        s += __shfl_xor(s, 2);
        if (cq == 0) out[m0 + m] = s + b6[0];
    }
}

extern "C" void kernel_launch(void* const* d_in, const int* in_sizes, int n_in,
                              void* d_out, int out_size, void* d_ws, size_t ws_size,
                              hipStream_t stream) {
    const float* coords = (const float*)d_in[0];
    const float* W1 = (const float*)d_in[1];
    const float* b1 = (const float*)d_in[2];
    const float* W2 = (const float*)d_in[3];
    const float* b2 = (const float*)d_in[4];
    const float* W3 = (const float*)d_in[5];
    const float* b3 = (const float*)d_in[6];
    const float* W4 = (const float*)d_in[7];
    const float* b4 = (const float*)d_in[8];
    const float* W5 = (const float*)d_in[9];
    const float* b5 = (const float*)d_in[10];
    const float* W6 = (const float*)d_in[11];
    const float* b6 = (const float*)d_in[12];
    float* out = (float*)d_out;

    unsigned short* whi = (unsigned short*)d_ws;        // 4*65536 ushorts = 512 KB
    unsigned short* wlo = whi + 4 * 65536;              // 512 KB (ws total 1 MB)

    prep_weights<<<1024, 256, 0, stream>>>(W2, W3, W4, W5, whi, wlo);

    const int nblocks = out_size / MT;                  // 524288 / 64 = 8192
    mlp_fused<<<nblocks, 256, 0, stream>>>(coords, W1, b1, b2, b3, b4, b5,
                                           W6, b6, whi, wlo, out);
}